// Round 1
// baseline (435.126 us; speedup 1.0000x reference)
//
#include <hip/hip_runtime.h>
#include <stdint.h>

// Problem constants (B,S,D,A fixed by the reference)
#define B_ 64
#define S_ 2048
#define D_ 512
#define A_ 256
#define TM 64          // tokens per block
#define NTILES 32      // S_/TM tiles per batch row
#define EPS 1e-7f

typedef short bf16x8 __attribute__((ext_vector_type(8)));
typedef float f32x4  __attribute__((ext_vector_type(4)));

// Workspace layout (bytes):
//  [0,       262144)   Wt   bf16 [A_][D_]  (W transposed, k-contiguous rows)
//  [262144, 4456448)   part f32  [B_*NTILES][D_]  (written every call, no zeroing needed)
//  [4456448,4456704)   Z    f32  [B_]
//  [4456704,4456708)   mask-mode flag: 1 = byte mask, 0 = 4-byte mask (int32/float32)
#define WS_WT   0
#define WS_PART 262144
#define WS_Z    4456448
#define WS_FLAG 4456704

__device__ __forceinline__ uint32_t f32pair_to_bf16(float a, float b) {
  // round-to-nearest-even fp32 -> bf16, packed (a = low half / lower k index)
  uint32_t ua = __float_as_uint(a), ub = __float_as_uint(b);
  ua = (ua + 0x7fffu + ((ua >> 16) & 1u)) >> 16;
  ub = (ub + 0x7fffu + ((ub >> 16) & 1u)) & 0xffff0000u;
  return ua | ub;
}

__global__ __launch_bounds__(256) void prep_kernel(
    const float* __restrict__ W, const void* __restrict__ mask,
    uint16_t* __restrict__ Wt, float* __restrict__ Z, int* __restrict__ flag)
{
  int i = blockIdx.x * 256 + threadIdx.x;
  if (i < A_ * D_) {
    int a = i >> 9;            // D_=512
    int d = i & (D_ - 1);
    uint32_t u = __float_as_uint(W[d * A_ + a]);
    u = (u + 0x7fffu + ((u >> 16) & 1u)) >> 16;
    Wt[i] = (uint16_t)u;       // Wt[a][d]
  } else if (i < A_ * D_ + B_) {
    Z[i - A_ * D_] = 0.0f;
  }
  // Mask encoding detection: one wave scans the first 4KB (in-bounds for any encoding).
  // int8-packed words have all bytes in {0,1} with some byte1..3 nonzero;
  // int32 0/1 words have bytes1..3 == 0; float32 words are 0 or 0x3f800000 (byte3=0x3f).
  if (blockIdx.x == 0 && threadIdx.x < 64) {
    const uint32_t* mw = (const uint32_t*)mask;
    int hit = 0;
    for (int k = 0; k < 16; ++k) {
      uint32_t v = mw[threadIdx.x + 64 * k];
      uint32_t b0 = v & 0xff, b1 = (v >> 8) & 0xff, b2 = (v >> 16) & 0xff, b3 = v >> 24;
      if (b0 <= 1u && b1 <= 1u && b2 <= 1u && b3 <= 1u && (b1 | b2 | b3)) hit = 1;
    }
    hit = __any(hit);
    if (threadIdx.x == 0) *flag = hit ? 1 : 0;
  }
}

__global__ __launch_bounds__(256, 2) void att_main(
    const float* __restrict__ x, const void* __restrict__ mask,
    const float* __restrict__ bias, const float* __restrict__ uvec,
    const uint16_t* __restrict__ Wt, float* __restrict__ part,
    float* __restrict__ Z, const int* __restrict__ flag)
{
  // XOR-swizzled bf16 tile: logical (row, chunk c of 8 k's) stored at chunk c ^ (row&7).
  // Keeps A-fragment ds_read_b128 and numerator-phase reads at <=2-way bank aliasing (free).
  __shared__ uint16_t xs[TM * D_];   // 65536 B
  __shared__ float sp[4][TM];        // cross-wave score partials
  __shared__ float ev[TM];           // unnormalized weights e_s

  const int tid  = threadIdx.x;
  const int bx   = blockIdx.x;
  const int b    = bx >> 5;          // NTILES = 32
  const int tile = bx & 31;
  const int s0   = tile * TM;

  // ---- stage x tile: fp32 global -> bf16 LDS (coalesced 32B/lane loads) ----
  const float* xb = x + ((size_t)b * S_ + (size_t)s0) * D_;
  #pragma unroll
  for (int c = 0; c < 16; ++c) {
    int p   = c * 256 + tid;         // 4096 chunks of 8 floats
    int row = p >> 6;
    int ch  = p & 63;
    const float* src = xb + row * D_ + ch * 8;
    float4 v0 = *(const float4*)(src);
    float4 v1 = *(const float4*)(src + 4);
    uint4 pk;
    pk.x = f32pair_to_bf16(v0.x, v0.y);
    pk.y = f32pair_to_bf16(v0.z, v0.w);
    pk.z = f32pair_to_bf16(v1.x, v1.y);
    pk.w = f32pair_to_bf16(v1.z, v1.w);
    int cc = ch ^ (row & 7);
    *(uint4*)(&xs[row * D_ + cc * 8]) = pk;
  }
  __syncthreads();

  // ---- MFMA: wave w computes pre-act for all 64 tokens x n in [64w, 64w+64) ----
  const int l  = tid & 63;
  const int w  = tid >> 6;
  const int lr = l & 15;   // A: token-within-16; B: n-within-16; C: col (=n)
  const int lg = l >> 4;   // k-group; C: row-group

  f32x4 acc[4][4];
  #pragma unroll
  for (int mt = 0; mt < 4; ++mt)
    #pragma unroll
    for (int nt = 0; nt < 4; ++nt)
      acc[mt][nt] = (f32x4){0.f, 0.f, 0.f, 0.f};

  const uint16_t* WtBase = Wt + (size_t)(w * 64 + lr) * D_;

  #pragma unroll 4
  for (int ks = 0; ks < 16; ++ks) {
    bf16x8 af[4], bfr[4];
    #pragma unroll
    for (int mt = 0; mt < 4; ++mt) {
      int row = mt * 16 + lr;
      int cc  = (ks * 4 + lg) ^ (lr & 7);
      af[mt]  = *(const bf16x8*)(&xs[row * D_ + cc * 8]);
    }
    #pragma unroll
    for (int nt = 0; nt < 4; ++nt)
      bfr[nt] = *(const bf16x8*)(WtBase + nt * 16 * D_ + ks * 32 + lg * 8);
    #pragma unroll
    for (int mt = 0; mt < 4; ++mt)
      #pragma unroll
      for (int nt = 0; nt < 4; ++nt)
        acc[mt][nt] = __builtin_amdgcn_mfma_f32_16x16x32_bf16(af[mt], bfr[nt], acc[mt][nt], 0, 0, 0);
  }

  // ---- epilogue: uit = tanh(acc + bias); partial score = sum over wave's 64 n ----
  float bn[4], un[4];
  #pragma unroll
  for (int nt = 0; nt < 4; ++nt) {
    int n = w * 64 + nt * 16 + lr;
    bn[nt] = bias[n];
    un[nt] = uvec[n];
  }
  #pragma unroll
  for (int mt = 0; mt < 4; ++mt) {
    #pragma unroll
    for (int r = 0; r < 4; ++r) {
      float ssum = 0.0f;
      #pragma unroll
      for (int nt = 0; nt < 4; ++nt) {
        float v  = acc[mt][nt][r] + bn[nt];
        float av = fabsf(v);
        float e2 = __expf(-2.0f * av);
        float t  = (1.0f - e2) / (1.0f + e2);   // tanh(|v|)
        ssum += copysignf(t, v) * un[nt];
      }
      // reduce across the 16 cols (lanes sharing lg)
      ssum += __shfl_xor(ssum, 1);
      ssum += __shfl_xor(ssum, 2);
      ssum += __shfl_xor(ssum, 4);
      ssum += __shfl_xor(ssum, 8);
      if (lr == 0) sp[w][mt * 16 + lg * 4 + r] = ssum;
    }
  }
  __syncthreads();

  // ---- e_s = exp(score)*mask; Z += sum(e) ----
  if (tid < TM) {
    float score = sp[0][tid] + sp[1][tid] + sp[2][tid] + sp[3][tid];
    int midx = b * S_ + s0 + tid;
    int mval;
    if (*flag) mval = ((const unsigned char*)mask)[midx] != 0;
    else       mval = ((const int*)mask)[midx] != 0;   // covers int32 and float32 encodings
    float e = mval ? __expf(score) : 0.0f;
    ev[tid] = e;
    float tot = e;
    #pragma unroll
    for (int o = 1; o < 64; o <<= 1) tot += __shfl_xor(tot, o);
    if (tid == 0) atomicAdd(&Z[b], tot);
  }
  __syncthreads();

  // ---- numerator partial: part[bx][d] = sum_s e_s * x[s][d] (fp32 accum) ----
  {
    int d0 = tid * 2;
    int c0 = d0 >> 3;
    int j  = d0 & 7;
    float a0 = 0.0f, a1 = 0.0f;
    for (int s = 0; s < TM; ++s) {
      int cc = c0 ^ (s & 7);
      uint32_t v = *(const uint32_t*)(&xs[s * D_ + cc * 8 + j]);
      float e = ev[s];
      a0 = fmaf(e, __uint_as_float(v << 16), a0);
      a1 = fmaf(e, __uint_as_float(v & 0xffff0000u), a1);
    }
    float2 st; st.x = a0; st.y = a1;
    *(float2*)(&part[(size_t)bx * D_ + d0]) = st;
  }
}

__global__ __launch_bounds__(256) void scale_kernel(
    const float* __restrict__ part, const float* __restrict__ Z,
    float* __restrict__ out)
{
  int idx = blockIdx.x * 256 + threadIdx.x;   // 32768 = B_*D_
  int b = idx >> 9;
  int d = idx & (D_ - 1);
  float s = 0.0f;
  #pragma unroll 8
  for (int t = 0; t < NTILES; ++t)
    s += part[(size_t)(b * NTILES + t) * D_ + d];
  out[idx] = s / (Z[b] + EPS);
}

extern "C" void kernel_launch(void* const* d_in, const int* in_sizes, int n_in,
                              void* d_out, int out_size, void* d_ws, size_t ws_size,
                              hipStream_t stream)
{
  const float* x    = (const float*)d_in[0];
  const void*  mask = d_in[1];
  const float* W    = (const float*)d_in[2];
  const float* bias = (const float*)d_in[3];
  const float* u    = (const float*)d_in[4];
  float* out = (float*)d_out;

  char* ws = (char*)d_ws;
  uint16_t* Wt  = (uint16_t*)(ws + WS_WT);
  float* part   = (float*)(ws + WS_PART);
  float* Z      = (float*)(ws + WS_Z);
  int*   flag   = (int*)(ws + WS_FLAG);

  int prep_threads = A_ * D_ + B_;
  prep_kernel<<<(prep_threads + 255) / 256, 256, 0, stream>>>(W, mask, Wt, Z, flag);
  att_main<<<B_ * NTILES, 256, 0, stream>>>(x, mask, bias, u, Wt, part, Z, flag);
  scale_kernel<<<(B_ * D_ + 255) / 256, 256, 0, stream>>>(part, Z, out);
}